// Round 1
// baseline (16512.296 us; speedup 1.0000x reference)
//
#include <hip/hip_runtime.h>

namespace {

constexpr int kNU = 100000;
constexpr int kNI = 50000;
constexpr int kN  = 150000;   // total nodes
constexpr int kH  = 128;
constexpr int kHh = 64;
constexpr int kEP = 2000000;
constexpr int kEN = 1000000;
constexpr int kL  = 2;        // inner layers

// ---- degree counting ----
__global__ void count_kernel(const int* __restrict__ dst, int E, float* __restrict__ cnt) {
  int t = blockIdx.x * blockDim.x + threadIdx.x;
  if (t < E) atomicAdd(&cnt[dst[t]], 1.0f);
}

__global__ void inv_kernel(float* __restrict__ c, int n) {
  int t = blockIdx.x * blockDim.x + threadIdx.x;
  if (t < n) c[t] = 1.0f / fmaxf(c[t], 1.0f);
}

// ---- scatter-add aggregation: agg[dst, aoff:aoff+W] += zsrc[src, soff:soff+W] ----
// One thread handles one float4 of one edge. WQ = W/4 (power of two).
template <int LOGWQ>
__global__ void agg_kernel(const int* __restrict__ src, const int* __restrict__ dst, int E,
                           const float* __restrict__ zsrc, int soff,
                           float* __restrict__ agg, int aoff) {
  constexpr int WQ = 1 << LOGWQ;
  int t = blockIdx.x * blockDim.x + threadIdx.x;
  if (t >= (E << LOGWQ)) return;
  int e = t >> LOGWQ;
  int c = (t & (WQ - 1)) << 2;
  int s = src[e];
  int d = dst[e];
  float4 v = *reinterpret_cast<const float4*>(zsrc + s * kH + soff + c);
  float* o = agg + d * kH + aoff + c;
  atomicAdd(o + 0, v.x);
  atomicAdd(o + 1, v.y);
  atomicAdd(o + 2, v.z);
  atomicAdd(o + 3, v.w);
}

// ---- row scaling: cols [0,64) *= invA[row], cols [64,128) *= invB[row] ----
__global__ void scale_kernel(float* __restrict__ agg, const float* __restrict__ invA,
                             const float* __restrict__ invB) {
  int t = blockIdx.x * blockDim.x + threadIdx.x;
  int row = t >> 5;
  if (row >= kN) return;
  int c = (t & 31) << 2;
  float inv = (c < kHh) ? invA[row] : invB[row];
  float4* p = reinterpret_cast<float4*>(agg + row * kH + c);
  float4 v = *p;
  v.x *= inv; v.y *= inv; v.z *= inv; v.w *= inv;
  *p = v;
}

// ---- fused GEMM: out[:, ooff:ooff+64] = relu(A1 @ W1 + A2[:, off2:off2+K2] @ W2 + bias)
// A1 is (N,128) read full-width (K1=128). Weights staged in LDS.
// Block: 256 threads -> 16 rows x 64 cols, 4 rows per thread.
template <int K2>
__global__ __launch_bounds__(256) void gemm_kernel(
    const float* __restrict__ A1, const float* __restrict__ W1,
    const float* __restrict__ A2, int off2, const float* __restrict__ W2,
    const float* __restrict__ bias, float* __restrict__ out, int ooff) {
  constexpr int K1 = kH;
  __shared__ float wl[K1 * kHh];
  __shared__ float wr[K2 * kHh];
  const int tid = threadIdx.x;
  for (int i = tid; i < K1 * kHh; i += 256) wl[i] = W1[i];
  for (int i = tid; i < K2 * kHh; i += 256) wr[i] = W2[i];
  __syncthreads();

  const int col = tid & 63;
  const int rg  = tid >> 6;
  const int row0 = blockIdx.x * 16 + rg * 4;
  const float b = bias[col];
  float acc0 = b, acc1 = b, acc2 = b, acc3 = b;

  {
    const float* a = A1 + row0 * kH;
#pragma unroll 4
    for (int k = 0; k < K1; k += 4) {
      float4 v0 = *reinterpret_cast<const float4*>(a + k);
      float4 v1 = *reinterpret_cast<const float4*>(a + kH + k);
      float4 v2 = *reinterpret_cast<const float4*>(a + 2 * kH + k);
      float4 v3 = *reinterpret_cast<const float4*>(a + 3 * kH + k);
      float w0 = wl[(k + 0) * kHh + col];
      float w1 = wl[(k + 1) * kHh + col];
      float w2 = wl[(k + 2) * kHh + col];
      float w3 = wl[(k + 3) * kHh + col];
      acc0 = fmaf(v0.w, w3, fmaf(v0.z, w2, fmaf(v0.y, w1, fmaf(v0.x, w0, acc0))));
      acc1 = fmaf(v1.w, w3, fmaf(v1.z, w2, fmaf(v1.y, w1, fmaf(v1.x, w0, acc1))));
      acc2 = fmaf(v2.w, w3, fmaf(v2.z, w2, fmaf(v2.y, w1, fmaf(v2.x, w0, acc2))));
      acc3 = fmaf(v3.w, w3, fmaf(v3.z, w2, fmaf(v3.y, w1, fmaf(v3.x, w0, acc3))));
    }
  }
  {
    const float* a = A2 + row0 * kH + off2;
#pragma unroll 4
    for (int k = 0; k < K2; k += 4) {
      float4 v0 = *reinterpret_cast<const float4*>(a + k);
      float4 v1 = *reinterpret_cast<const float4*>(a + kH + k);
      float4 v2 = *reinterpret_cast<const float4*>(a + 2 * kH + k);
      float4 v3 = *reinterpret_cast<const float4*>(a + 3 * kH + k);
      float w0 = wr[(k + 0) * kHh + col];
      float w1 = wr[(k + 1) * kHh + col];
      float w2 = wr[(k + 2) * kHh + col];
      float w3 = wr[(k + 3) * kHh + col];
      acc0 = fmaf(v0.w, w3, fmaf(v0.z, w2, fmaf(v0.y, w1, fmaf(v0.x, w0, acc0))));
      acc1 = fmaf(v1.w, w3, fmaf(v1.z, w2, fmaf(v1.y, w1, fmaf(v1.x, w0, acc1))));
      acc2 = fmaf(v2.w, w3, fmaf(v2.z, w2, fmaf(v2.y, w1, fmaf(v2.x, w0, acc2))));
      acc3 = fmaf(v3.w, w3, fmaf(v3.z, w2, fmaf(v3.y, w1, fmaf(v3.x, w0, acc3))));
    }
  }
  float* o = out + row0 * kH + ooff + col;
  o[0 * kH] = fmaxf(acc0, 0.0f);
  o[1 * kH] = fmaxf(acc1, 0.0f);
  o[2 * kH] = fmaxf(acc2, 0.0f);
  o[3 * kH] = fmaxf(acc3, 0.0f);
}

}  // namespace

extern "C" void kernel_launch(void* const* d_in, const int* in_sizes, int n_in,
                              void* d_out, int out_size, void* d_ws, size_t ws_size,
                              hipStream_t stream) {
  const int*   pos     = (const int*)d_in[0];
  const int*   neg     = (const int*)d_in[1];
  const float* users   = (const float*)d_in[2];
  const float* items   = (const float*)d_in[3];
  const float* c1_wpl  = (const float*)d_in[4];
  const float* c1_wpr  = (const float*)d_in[5];
  const float* c1_bpr  = (const float*)d_in[6];
  const float* c1_wnl  = (const float*)d_in[7];
  const float* c1_wnr  = (const float*)d_in[8];
  const float* c1_bnr  = (const float*)d_in[9];
  const float* cw_pl   = (const float*)d_in[10];
  const float* cw_pr   = (const float*)d_in[11];
  const float* cb_pr   = (const float*)d_in[12];
  const float* cw_nl   = (const float*)d_in[13];
  const float* cw_nr   = (const float*)d_in[14];
  const float* cb_nr   = (const float*)d_in[15];
  float* out = (float*)d_out;

  // workspace layout: invp[N] | invn[N] | bufA[N*128] | agg[N*128]
  const size_t need = ((size_t)2 * kN + (size_t)2 * kN * kH) * sizeof(float);
  if (ws_size < need) return;  // insufficient scratch: fail visibly
  float* ws   = (float*)d_ws;
  float* invp = ws;
  float* invn = ws + kN;
  float* bufA = ws + 2 * (size_t)kN;
  float* agg  = bufA + (size_t)kN * kH;
  const size_t aggBytes = (size_t)kN * kH * sizeof(float);

  const int* pos_src = pos;
  const int* pos_dst = pos + kEP;
  const int* neg_src = neg;
  const int* neg_dst = neg + kEN;

  // x = concat(users, items) into bufA
  hipMemcpyAsync(bufA, users, (size_t)kNU * kH * sizeof(float),
                 hipMemcpyDeviceToDevice, stream);
  hipMemcpyAsync(bufA + (size_t)kNU * kH, items, (size_t)kNI * kH * sizeof(float),
                 hipMemcpyDeviceToDevice, stream);

  // degree counts -> reciprocals (shared by all layers)
  hipMemsetAsync(invp, 0, (size_t)2 * kN * sizeof(float), stream);
  count_kernel<<<(kEP + 255) / 256, 256, 0, stream>>>(pos_dst, kEP, invp);
  count_kernel<<<(kEN + 255) / 256, 256, 0, stream>>>(neg_dst, kEN, invn);
  inv_kernel<<<(2 * kN + 255) / 256, 256, 0, stream>>>(invp, 2 * kN);

  const int gP5 = (kEP * 32) / 256;  // W=128 over pos edges
  const int gN5 = (kEN * 32) / 256;
  const int gP4 = (kEP * 16) / 256;  // W=64 over pos edges
  const int gN4 = (kEN * 16) / 256;
  const int gS  = (kN * 32 + 255) / 256;
  const int gG  = kN / 16;

  // ---- layer 1 ----
  // positive half: out[:, :64] = relu(mean_p(x) @ c1_wpl + x @ c1_wpr + c1_bpr)
  hipMemsetAsync(agg, 0, aggBytes, stream);
  agg_kernel<5><<<gP5, 256, 0, stream>>>(pos_src, pos_dst, kEP, bufA, 0, agg, 0);
  scale_kernel<<<gS, 256, 0, stream>>>(agg, invp, invp);
  gemm_kernel<128><<<gG, 256, 0, stream>>>(agg, c1_wpl, bufA, 0, c1_wpr, c1_bpr, out, 0);
  // negative half
  hipMemsetAsync(agg, 0, aggBytes, stream);
  agg_kernel<5><<<gN5, 256, 0, stream>>>(neg_src, neg_dst, kEN, bufA, 0, agg, 0);
  scale_kernel<<<gS, 256, 0, stream>>>(agg, invn, invn);
  gemm_kernel<128><<<gG, 256, 0, stream>>>(agg, c1_wnl, bufA, 0, c1_wnr, c1_bnr, out, kHh);

  // ---- inner layers ----
  float* zin  = out;   // layer-1 output lives in d_out
  float* zout = bufA;  // x no longer needed
  for (int l = 0; l < kL; ++l) {
    const float* wpl = cw_pl + (size_t)l * kH * kHh;
    const float* wpr = cw_pr + (size_t)l * kHh * kHh;
    const float* bpr = cb_pr + (size_t)l * kHh;
    const float* wnl = cw_nl + (size_t)l * kH * kHh;
    const float* wnr = cw_nr + (size_t)l * kHh * kHh;
    const float* bnr = cb_nr + (size_t)l * kHh;

    // positive half: concat(a_pp, a_nn) @ wpl + zp @ wpr
    hipMemsetAsync(agg, 0, aggBytes, stream);
    agg_kernel<4><<<gP4, 256, 0, stream>>>(pos_src, pos_dst, kEP, zin, 0,   agg, 0);
    agg_kernel<4><<<gN4, 256, 0, stream>>>(neg_src, neg_dst, kEN, zin, kHh, agg, kHh);
    scale_kernel<<<gS, 256, 0, stream>>>(agg, invp, invn);
    gemm_kernel<64><<<gG, 256, 0, stream>>>(agg, wpl, zin, 0, wpr, bpr, zout, 0);

    // negative half: concat(a_np, a_pn) @ wnl + zn @ wnr
    hipMemsetAsync(agg, 0, aggBytes, stream);
    agg_kernel<4><<<gP4, 256, 0, stream>>>(pos_src, pos_dst, kEP, zin, kHh, agg, 0);
    agg_kernel<4><<<gN4, 256, 0, stream>>>(neg_src, neg_dst, kEN, zin, 0,   agg, kHh);
    scale_kernel<<<gS, 256, 0, stream>>>(agg, invp, invn);
    gemm_kernel<64><<<gG, 256, 0, stream>>>(agg, wnl, zin, kHh, wnr, bnr, zout, kHh);

    float* tmp = zin; zin = zout; zout = tmp;
  }
  // after 2 swaps zin == out: final result already in d_out
}

// Round 2
// 2554.729 us; speedup vs baseline: 6.4634x; 6.4634x over previous
//
#include <hip/hip_runtime.h>

namespace {

constexpr int kNU = 100000;
constexpr int kNI = 50000;
constexpr int kN  = 150000;
constexpr int kH  = 128;
constexpr int kEP = 2000000;
constexpr int kEN = 1000000;
constexpr int kL  = 2;

constexpr int SCAN_BS = 256;
constexpr int SCAN_IT = 4;                    // items/thread
constexpr int SCAN_TILE = SCAN_BS * SCAN_IT;  // 1024 items/block

// ---- degree counting (int) ----
__global__ void count_kernel(const int* __restrict__ dst, int E, int* __restrict__ deg) {
  int t = blockIdx.x * blockDim.x + threadIdx.x;
  if (t < E) atomicAdd(&deg[dst[t]], 1);
}

__global__ void inv_kernel(const int* __restrict__ deg, float* __restrict__ inv, int n) {
  int t = blockIdx.x * blockDim.x + threadIdx.x;
  if (t < n) inv[t] = 1.0f / fmaxf((float)deg[t], 1.0f);
}

// ---- 3-phase exclusive scan: deg[0..n) -> off[0..n] ----
__global__ void scan_partial(const int* __restrict__ deg, int n,
                             int* __restrict__ off, int* __restrict__ sums) {
  __shared__ int sh[SCAN_BS];
  const int t = threadIdx.x;
  const int base = blockIdx.x * SCAN_TILE;
  int v[SCAN_IT];
  int run = 0;
#pragma unroll
  for (int j = 0; j < SCAN_IT; ++j) {
    int idx = base + t * SCAN_IT + j;
    v[j] = (idx < n) ? deg[idx] : 0;
    run += v[j];
  }
  sh[t] = run;
  __syncthreads();
  for (int d = 1; d < SCAN_BS; d <<= 1) {
    int x = (t >= d) ? sh[t - d] : 0;
    __syncthreads();
    sh[t] += x;
    __syncthreads();
  }
  int acc = sh[t] - run;  // exclusive prefix of this thread within block
  if (t == SCAN_BS - 1) sums[blockIdx.x] = sh[t];
#pragma unroll
  for (int j = 0; j < SCAN_IT; ++j) {
    int idx = base + t * SCAN_IT + j;
    acc += v[j];
    if (idx < n) off[idx + 1] = acc;  // inclusive within block
  }
}

__global__ void scan_sums(int* __restrict__ sums, int nb) {
  __shared__ int sh[SCAN_BS];
  const int t = threadIdx.x;
  int v = (t < nb) ? sums[t] : 0;
  sh[t] = v;
  __syncthreads();
  for (int d = 1; d < SCAN_BS; d <<= 1) {
    int x = (t >= d) ? sh[t - d] : 0;
    __syncthreads();
    sh[t] += x;
    __syncthreads();
  }
  if (t < nb) sums[t] = sh[t] - v;  // exclusive block offsets
}

__global__ void scan_add(int* __restrict__ off, int n, const int* __restrict__ sums) {
  int t = blockIdx.x * blockDim.x + threadIdx.x;
  if (t == 0) off[0] = 0;
  if (t < n) off[t + 1] += sums[t / SCAN_TILE];
}

// ---- CSR fill: eids[bucket(dst)] = src ----
__global__ void fill_kernel(const int* __restrict__ src, const int* __restrict__ dst, int E,
                            int* __restrict__ cursor, int* __restrict__ eids) {
  int t = blockIdx.x * blockDim.x + threadIdx.x;
  if (t < E) {
    int p = atomicAdd(&cursor[dst[t]], 1);
    eids[p] = src[t];
  }
}

// ---- CSR gather-mean: agg[row,:] = mean over bucket of z[src,:], full 128 wide ----
// 32 lanes per row (float4/lane), 8 rows per 256-thread block.
template <bool SPLIT>
__global__ __launch_bounds__(256) void agg_csr(
    const int* __restrict__ off, const int* __restrict__ eids,
    const float* __restrict__ inv,
    const float* __restrict__ zu, const float* __restrict__ zi,
    float* __restrict__ aggOut) {
  const int g = threadIdx.x >> 5;
  const int lane = threadIdx.x & 31;
  const int row = blockIdx.x * 8 + g;
  if (row >= kN) return;
  const int s = off[row], e = off[row + 1];
  float4 acc = make_float4(0.f, 0.f, 0.f, 0.f);
  int i = s;
  for (; i + 2 <= e; i += 2) {
    int s0 = eids[i], s1 = eids[i + 1];
    const float* r0;
    const float* r1;
    if (SPLIT) {
      r0 = (s0 < kNU) ? zu + (size_t)s0 * kH : zi + (size_t)(s0 - kNU) * kH;
      r1 = (s1 < kNU) ? zu + (size_t)s1 * kH : zi + (size_t)(s1 - kNU) * kH;
    } else {
      r0 = zu + (size_t)s0 * kH;
      r1 = zu + (size_t)s1 * kH;
    }
    float4 v0 = *reinterpret_cast<const float4*>(r0 + lane * 4);
    float4 v1 = *reinterpret_cast<const float4*>(r1 + lane * 4);
    acc.x += v0.x + v1.x; acc.y += v0.y + v1.y;
    acc.z += v0.z + v1.z; acc.w += v0.w + v1.w;
  }
  if (i < e) {
    int s0 = eids[i];
    const float* r0;
    if (SPLIT) r0 = (s0 < kNU) ? zu + (size_t)s0 * kH : zi + (size_t)(s0 - kNU) * kH;
    else r0 = zu + (size_t)s0 * kH;
    float4 v0 = *reinterpret_cast<const float4*>(r0 + lane * 4);
    acc.x += v0.x; acc.y += v0.y; acc.z += v0.z; acc.w += v0.w;
  }
  const float sc = inv[row];
  float4 r = make_float4(acc.x * sc, acc.y * sc, acc.z * sc, acc.w * sc);
  *reinterpret_cast<float4*>(aggOut + (size_t)row * kH + lane * 4) = r;
}

// ---- fused GEMM half-layer ----
// out[:, ooff:+64] = relu( P1[:, o1:+64] @ W1[0:64,:] + P2[:, o2:+64] @ W1[64:128,:]
//                          + X[:, oz:+K2] @ W2 + bias )
// X[r] = Xu[r] (SPLITX=false) or users/items split (SPLITX=true).
// In-place safe (out may alias Xu): __syncthreads() separates reads from writes;
// rows are block-exclusive.
template <int K2, bool SPLITX>
__global__ __launch_bounds__(256) void gemm2(
    const float* __restrict__ P1, int o1,
    const float* __restrict__ P2, int o2,
    const float* __restrict__ W1,   // 128 x 64
    const float* __restrict__ Xu, const float* __restrict__ Xi, int oz,
    const float* __restrict__ W2,   // K2 x 64
    const float* __restrict__ bias,
    float* __restrict__ out, int ooff) {
  __shared__ float wl[128 * 64];
  __shared__ float wr[K2 * 64];
  const int tid = threadIdx.x;
  for (int i = tid; i < 128 * 64; i += 256) wl[i] = W1[i];
  for (int i = tid; i < K2 * 64; i += 256) wr[i] = W2[i];
  __syncthreads();

  const int col = tid & 63;
  const int rg  = tid >> 6;
  const int row0 = blockIdx.x * 16 + rg * 4;
  const float b = bias[col];
  float acc0 = b, acc1 = b, acc2 = b, acc3 = b;

  {
    const float* a = P1 + (size_t)row0 * kH + o1;
#pragma unroll 4
    for (int k = 0; k < 64; k += 4) {
      float4 v0 = *reinterpret_cast<const float4*>(a + k);
      float4 v1 = *reinterpret_cast<const float4*>(a + kH + k);
      float4 v2 = *reinterpret_cast<const float4*>(a + 2 * kH + k);
      float4 v3 = *reinterpret_cast<const float4*>(a + 3 * kH + k);
      float w0 = wl[(k + 0) * 64 + col];
      float w1 = wl[(k + 1) * 64 + col];
      float w2 = wl[(k + 2) * 64 + col];
      float w3 = wl[(k + 3) * 64 + col];
      acc0 = fmaf(v0.w, w3, fmaf(v0.z, w2, fmaf(v0.y, w1, fmaf(v0.x, w0, acc0))));
      acc1 = fmaf(v1.w, w3, fmaf(v1.z, w2, fmaf(v1.y, w1, fmaf(v1.x, w0, acc1))));
      acc2 = fmaf(v2.w, w3, fmaf(v2.z, w2, fmaf(v2.y, w1, fmaf(v2.x, w0, acc2))));
      acc3 = fmaf(v3.w, w3, fmaf(v3.z, w2, fmaf(v3.y, w1, fmaf(v3.x, w0, acc3))));
    }
  }
  {
    const float* a = P2 + (size_t)row0 * kH + o2;
#pragma unroll 4
    for (int k = 0; k < 64; k += 4) {
      float4 v0 = *reinterpret_cast<const float4*>(a + k);
      float4 v1 = *reinterpret_cast<const float4*>(a + kH + k);
      float4 v2 = *reinterpret_cast<const float4*>(a + 2 * kH + k);
      float4 v3 = *reinterpret_cast<const float4*>(a + 3 * kH + k);
      float w0 = wl[(64 + k + 0) * 64 + col];
      float w1 = wl[(64 + k + 1) * 64 + col];
      float w2 = wl[(64 + k + 2) * 64 + col];
      float w3 = wl[(64 + k + 3) * 64 + col];
      acc0 = fmaf(v0.w, w3, fmaf(v0.z, w2, fmaf(v0.y, w1, fmaf(v0.x, w0, acc0))));
      acc1 = fmaf(v1.w, w3, fmaf(v1.z, w2, fmaf(v1.y, w1, fmaf(v1.x, w0, acc1))));
      acc2 = fmaf(v2.w, w3, fmaf(v2.z, w2, fmaf(v2.y, w1, fmaf(v2.x, w0, acc2))));
      acc3 = fmaf(v3.w, w3, fmaf(v3.z, w2, fmaf(v3.y, w1, fmaf(v3.x, w0, acc3))));
    }
  }
  {
    const float* xr[4];
#pragma unroll
    for (int j = 0; j < 4; ++j) {
      int r = row0 + j;
      if (SPLITX) xr[j] = (r < kNU) ? Xu + (size_t)r * kH : Xi + (size_t)(r - kNU) * kH;
      else        xr[j] = Xu + (size_t)r * kH;
      xr[j] += oz;
    }
#pragma unroll 4
    for (int k = 0; k < K2; k += 4) {
      float4 v0 = *reinterpret_cast<const float4*>(xr[0] + k);
      float4 v1 = *reinterpret_cast<const float4*>(xr[1] + k);
      float4 v2 = *reinterpret_cast<const float4*>(xr[2] + k);
      float4 v3 = *reinterpret_cast<const float4*>(xr[3] + k);
      float w0 = wr[(k + 0) * 64 + col];
      float w1 = wr[(k + 1) * 64 + col];
      float w2 = wr[(k + 2) * 64 + col];
      float w3 = wr[(k + 3) * 64 + col];
      acc0 = fmaf(v0.w, w3, fmaf(v0.z, w2, fmaf(v0.y, w1, fmaf(v0.x, w0, acc0))));
      acc1 = fmaf(v1.w, w3, fmaf(v1.z, w2, fmaf(v1.y, w1, fmaf(v1.x, w0, acc1))));
      acc2 = fmaf(v2.w, w3, fmaf(v2.z, w2, fmaf(v2.y, w1, fmaf(v2.x, w0, acc2))));
      acc3 = fmaf(v3.w, w3, fmaf(v3.z, w2, fmaf(v3.y, w1, fmaf(v3.x, w0, acc3))));
    }
  }
  __syncthreads();  // all X reads complete before in-place writes
  float* o = out + (size_t)row0 * kH + ooff + col;
  o[0 * kH] = fmaxf(acc0, 0.0f);
  o[1 * kH] = fmaxf(acc1, 0.0f);
  o[2 * kH] = fmaxf(acc2, 0.0f);
  o[3 * kH] = fmaxf(acc3, 0.0f);
}

inline float* align16(void* p) {
  return (float*)(((uintptr_t)p + 15) & ~(uintptr_t)15);
}

}  // namespace

extern "C" void kernel_launch(void* const* d_in, const int* in_sizes, int n_in,
                              void* d_out, int out_size, void* d_ws, size_t ws_size,
                              hipStream_t stream) {
  const int*   pos     = (const int*)d_in[0];
  const int*   neg     = (const int*)d_in[1];
  const float* users   = (const float*)d_in[2];
  const float* items   = (const float*)d_in[3];
  const float* c1_wpl  = (const float*)d_in[4];
  const float* c1_wpr  = (const float*)d_in[5];
  const float* c1_bpr  = (const float*)d_in[6];
  const float* c1_wnl  = (const float*)d_in[7];
  const float* c1_wnr  = (const float*)d_in[8];
  const float* c1_bnr  = (const float*)d_in[9];
  const float* cw_pl   = (const float*)d_in[10];
  const float* cw_pr   = (const float*)d_in[11];
  const float* cb_pr   = (const float*)d_in[12];
  const float* cw_nl   = (const float*)d_in[13];
  const float* cw_nr   = (const float*)d_in[14];
  const float* cb_nr   = (const float*)d_in[15];
  float* out = (float*)d_out;

  const int* pos_src = pos;
  const int* pos_dst = pos + kEP;
  const int* neg_src = neg;
  const int* neg_dst = neg + kEN;

  // ---- workspace layout ----
  float* invp = (float*)d_ws;            // kN
  float* invn = invp + kN;               // kN
  int* degp   = (int*)(invn + kN);       // kN (reused as cursor)
  int* degn   = degp + kN;               // kN
  int* offp   = degn + kN;               // kN+1
  int* offn   = offp + kN + 1;           // kN+1
  int* sums   = offn + kN + 1;           // 256
  int* eidp   = sums + 256;              // kEP
  int* eidn   = eidp + kEP;              // kEN
  float* aggP = align16(eidn + kEN);     // kN*128
  float* aggN = aggP + (size_t)kN * kH;  // kN*128
  const size_t need = (size_t)((char*)(aggN + (size_t)kN * kH) - (char*)d_ws);
  if (ws_size < need) return;

  const int nbP = (kN + SCAN_TILE - 1) / SCAN_TILE;  // 147

  // ---- degree counts + inverses ----
  hipMemsetAsync(degp, 0, (size_t)2 * kN * sizeof(int), stream);
  count_kernel<<<(kEP + 255) / 256, 256, 0, stream>>>(pos_dst, kEP, degp);
  count_kernel<<<(kEN + 255) / 256, 256, 0, stream>>>(neg_dst, kEN, degn);
  inv_kernel<<<(kN + 255) / 256, 256, 0, stream>>>(degp, invp, kN);
  inv_kernel<<<(kN + 255) / 256, 256, 0, stream>>>(degn, invn, kN);

  // ---- CSR build (pos) ----
  scan_partial<<<nbP, SCAN_BS, 0, stream>>>(degp, kN, offp, sums);
  scan_sums<<<1, SCAN_BS, 0, stream>>>(sums, nbP);
  scan_add<<<(kN + 255) / 256, 256, 0, stream>>>(offp, kN, sums);
  hipMemcpyAsync(degp, offp, (size_t)kN * sizeof(int), hipMemcpyDeviceToDevice, stream);
  fill_kernel<<<(kEP + 255) / 256, 256, 0, stream>>>(pos_src, pos_dst, kEP, degp, eidp);

  // ---- CSR build (neg) ----
  scan_partial<<<nbP, SCAN_BS, 0, stream>>>(degn, kN, offn, sums);
  scan_sums<<<1, SCAN_BS, 0, stream>>>(sums, nbP);
  scan_add<<<(kN + 255) / 256, 256, 0, stream>>>(offn, kN, sums);
  hipMemcpyAsync(degn, offn, (size_t)kN * sizeof(int), hipMemcpyDeviceToDevice, stream);
  fill_kernel<<<(kEN + 255) / 256, 256, 0, stream>>>(neg_src, neg_dst, kEN, degn, eidn);

  const int gA = (kN + 7) / 8;   // agg blocks (8 rows each)
  const int gG = kN / 16;        // gemm blocks (16 rows each)

  // ---- layer 1: aggregate x = concat(users, items) directly from inputs ----
  agg_csr<true><<<gA, 256, 0, stream>>>(offp, eidp, invp, users, items, aggP);
  agg_csr<true><<<gA, 256, 0, stream>>>(offn, eidn, invn, users, items, aggN);
  gemm2<128, true><<<gG, 256, 0, stream>>>(aggP, 0, aggP, 64, c1_wpl,
                                           users, items, 0, c1_wpr, c1_bpr, out, 0);
  gemm2<128, true><<<gG, 256, 0, stream>>>(aggN, 0, aggN, 64, c1_wnl,
                                           users, items, 0, c1_wnr, c1_bnr, out, 64);

  // ---- inner layers: z lives in d_out, updated in place ----
  for (int l = 0; l < kL; ++l) {
    const float* wpl = cw_pl + (size_t)l * kH * 64;
    const float* wpr = cw_pr + (size_t)l * 64 * 64;
    const float* bpr = cb_pr + (size_t)l * 64;
    const float* wnl = cw_nl + (size_t)l * kH * 64;
    const float* wnr = cw_nr + (size_t)l * 64 * 64;
    const float* bnr = cb_nr + (size_t)l * 64;

    // aggP = mean_p(z) = [a_pp | a_np]; aggN = mean_n(z) = [a_pn | a_nn]
    agg_csr<false><<<gA, 256, 0, stream>>>(offp, eidp, invp, out, nullptr, aggP);
    agg_csr<false><<<gA, 256, 0, stream>>>(offn, eidn, invn, out, nullptr, aggN);

    // out_pos = relu(concat(a_pp, a_nn) @ wpl + zp @ wpr + bpr)
    gemm2<64, false><<<gG, 256, 0, stream>>>(aggP, 0, aggN, 64, wpl,
                                             out, nullptr, 0, wpr, bpr, out, 0);
    // out_neg = relu(concat(a_np, a_pn) @ wnl + zn @ wnr + bnr)
    gemm2<64, false><<<gG, 256, 0, stream>>>(aggP, 64, aggN, 0, wnl,
                                             out, nullptr, 64, wnr, bnr, out, 64);
  }
}